// Round 8
// baseline (284.966 us; speedup 1.0000x reference)
//
#include <hip/hip_runtime.h>

#define DEVINL __device__ __forceinline__

typedef __bf16 bf16x8 __attribute__((ext_vector_type(8)));
typedef float  f32x4  __attribute__((ext_vector_type(4)));
typedef unsigned u32x2 __attribute__((ext_vector_type(2)));

// ---------------- constants / ws layout ----------------
// B=256, C=1024, H=64, E=64, K=2, MI=128, tokens T = 262144
static constexpr size_t kAdjOff  = 0;                 // 2*1024 f32 (8 KB)
static constexpr size_t kBiasOff = 8192;              // 64*3*4*64*4 f32 = 786432 B
static constexpr size_t kFragOff = 8192 + 786432;     // 112 frags * 1024 B = 114688 B

// B-fragment bases (units: one frag = 64 lanes * 16 B)
static constexpr int FB_Wn1h0 = 0,  FB_Wn1h1 = 8,  FB_Wn2_0 = 16, FB_Wn2_1 = 24;
static constexpr int FB_Ws1h  = 32, FB_Ws2   = 40, FB_We    = 48, FB_Wa    = 56;
static constexpr int FB_Wih   = 64, FB_Whh   = 88;

// ---------------- helpers ----------------
DEVINL unsigned short bf16r(float f) {           // RTNE float->bf16
  unsigned u = __builtin_bit_cast(unsigned, f);
  unsigned r = ((u >> 16) & 1u) + 0x7FFFu;
  return (unsigned short)((u + r) >> 16);
}
DEVINL float sigmoidf_(float x) { return __builtin_amdgcn_rcpf(1.f + __expf(-x)); }
DEVINL float tanhf_(float x)    { return 1.f - 2.f * __builtin_amdgcn_rcpf(1.f + __expf(2.f * x)); }

// HW packed f32->bf16 (RNE, matches bf16r semantics on in-range values)
DEVINL unsigned pkbf(float a, float b) {
  unsigned d;
  asm("v_cvt_pk_bf16_f32 %0, %1, %2" : "=v"(d) : "v"(a), "v"(b));
  return d;
}

DEVINL f32x4 mfma16(bf16x8 a, bf16x8 b, f32x4 c) {
  return __builtin_amdgcn_mfma_f32_16x16x32_bf16(a, b, c, 0, 0, 0);
}

DEVINL unsigned clip2_(unsigned x) {   // clamp two packed bf16 to [-5,5]; exact repack
  float lo = __builtin_bit_cast(float, x << 16);
  float hi = __builtin_bit_cast(float, x & 0xFFFF0000u);
  lo = fminf(fmaxf(lo, -5.f), 5.f);
  hi = fminf(fmaxf(hi, -5.f), 5.f);
  return (__builtin_bit_cast(unsigned, lo) >> 16) | (__builtin_bit_cast(unsigned, hi) & 0xFFFF0000u);
}
DEVINL bf16x8 clip5(bf16x8 a) {
  uint4 u = __builtin_bit_cast(uint4, a);
  u.x = clip2_(u.x); u.y = clip2_(u.y); u.z = clip2_(u.z); u.w = clip2_(u.w);
  return __builtin_bit_cast(bf16x8, u);
}

// DS ops as volatile asm, no "memory" clobber (r14): mutual program order between
// volatile asm blocks + in-order DS queue give hbuf write->read->overwrite safety;
// ordinary global loads stay free to pipeline. tr-read keeps its internal
// lgkmcnt(0) (proven correct r13b); outputs early-clobber.
DEVINL void dsw64(unsigned addr, unsigned long long d) {
  asm volatile("ds_write_b64 %0, %1" :: "v"(addr), "v"(d));
}
DEVINL void ldA2_tr(unsigned addr, bf16x8& a0, bf16x8& a1) {
  u32x2 r0, r1, r2, r3;
  asm volatile(
      "ds_read_b64_tr_b16 %0, %4\n\t"
      "ds_read_b64_tr_b16 %1, %4 offset:512\n\t"
      "ds_read_b64_tr_b16 %2, %4 offset:1024\n\t"
      "ds_read_b64_tr_b16 %3, %4 offset:1536\n\t"
      "s_waitcnt lgkmcnt(0)"
      : "=&v"(r0), "=&v"(r1), "=&v"(r2), "=&v"(r3)
      : "v"(addr));
  uint4 u0{r0.x, r0.y, r1.x, r1.y};
  uint4 u1{r2.x, r2.y, r3.x, r3.y};
  a0 = __builtin_bit_cast(bf16x8, u0);
  a1 = __builtin_bit_cast(bf16x8, u1);
}

// ---------------- prep 1: adjacency vector (SPARSE: a0 has ~5 nonzeros) ----------------
__global__ void prep_adj_kernel(const int* __restrict__ qt, const float* __restrict__ onehot,
                                const float* __restrict__ graphs, float* __restrict__ adjw) {
  __shared__ float a0v[1024];
  __shared__ int   aidx[1024];
  __shared__ int   s_nnz;
  __shared__ float s_den;
  const int tid = threadIdx.x;
  const int k = blockIdx.x >> 2, chunk = blockIdx.x & 3;   // 8 blocks: 2k x 4 chunks of 256 d
  if (tid == 0) { s_nnz = 0; s_den = 0.f; }
  __syncthreads();
  const int q0 = qt[0];
  float lsum = 0.f;
#pragma unroll
  for (int i = 0; i < 4; i++) {
    int c = tid * 4 + i;
    float v = onehot[(size_t)q0 * 1024 + c];
    lsum += v;
    if (v != 0.f) { int p = atomicAdd(&s_nnz, 1); aidx[p] = c; a0v[p] = v; }
  }
#pragma unroll
  for (int off = 32; off >= 1; off >>= 1) lsum += __shfl_xor(lsum, off, 64);
  if ((tid & 63) == 0) atomicAdd(&s_den, lsum);
  __syncthreads();
  const float denom = fmaxf(s_den, 1.f);
  const int nnz = s_nnz;
  const int d = chunk * 256 + tid;
  const float* G = graphs + (size_t)k * 1048576 + d;
  float sum = 0.f;
  for (int j = 0; j < nnz; j++) sum += a0v[j] * G[(size_t)aidx[j] * 1024];
  adjw[k * 1024 + d] = fminf(fmaxf(sum / denom, -5.f), 5.f);
}

// ---------------- prep 2: per-c bias tables (kc folded into layer-1 bias) ----------------
// biasTab layout: [c16(64)][tab(3: n_k0,n_k1,self)][nt(4)][lane(64)][r(4)] fp32
__global__ void prep_bias_kernel(const float* __restrict__ kc, const float* __restrict__ Wn1,
                                 const float* __restrict__ bn1, const float* __restrict__ Ws1,
                                 const float* __restrict__ bs1, float* __restrict__ biasTab) {
  int gid = blockIdx.x * 256 + threadIdx.x;   // 196608 total
  int j = gid & 63;
  int c = (gid >> 6) & 1023;
  int tab = gid >> 16;                        // 0,1 neigh-k; 2 self
  const float* kcr = kc + (size_t)c * 64;
  float s;
  if (tab < 2) {
    s = bn1[tab * 64 + j];
    const float* W = Wn1 + ((size_t)tab * 256 + 192) * 64 + j;   // kc rows of neigh net
#pragma unroll 4
    for (int e = 0; e < 64; e++) s += fminf(fmaxf(kcr[e], -5.f), 5.f) * W[(size_t)e * 64];
  } else {
    s = bs1[j];
    const float* W = Ws1 + (size_t)64 * 64 + j;                  // kc rows of self net (unclipped)
#pragma unroll 4
    for (int e = 0; e < 64; e++) s += kcr[e] * W[(size_t)e * 64];
  }
  int c16 = c >> 4, rr = c & 3, qq = (c & 15) >> 2, nt = j >> 4;
  int lane = qq * 16 + (j & 15);
  biasTab[(size_t)((((c16 * 3 + tab) * 4 + nt) * 64 + lane)) * 4 + rr] = s;
}

// ---------------- prep 3: weights -> bf16 B-fragments (pre-swizzled, pi-permuted) --------
// B-frag (16x16x32): lane l slot j holds B[k = ks*32 + pi(q,j)][n = nt*16 + (l&15)],
// q = l>>4, pi(q,j) = (j<4) ? q*4+j : 16 + q*4 + (j-4).
// pi matches the k-order ds_read_b64_tr_b16 delivers from the transposed hbuf.
__global__ void prep_wfrag_kernel(const float* __restrict__ Wn1, const float* __restrict__ Wn2,
                                  const float* __restrict__ Ws1, const float* __restrict__ Ws2,
                                  const float* __restrict__ We,  const float* __restrict__ Wa,
                                  const float* __restrict__ Wih, const float* __restrict__ Whh,
                                  uint4* __restrict__ wfrag) {
  const int bid = blockIdx.x, lane = threadIdx.x;   // 112 blocks x 64 threads
  int mat, ks, nt;
  if (bid < 64) { mat = bid >> 3; ks = (bid >> 2) & 1; nt = bid & 3; }
  else { int f2 = bid - 64; mat = 8 + f2 / 24; int f = f2 % 24; ks = f / 12; nt = f % 12; }
  const float* base = Wn1; int stride = 64;
  switch (mat) {
    case 0: base = Wn1 + (size_t)128 * 64; break;          // Wn1 k0, ht rows 128..191
    case 1: base = Wn1 + (size_t)(256 + 128) * 64; break;  // Wn1 k1
    case 2: base = Wn2; break;
    case 3: base = Wn2 + (size_t)64 * 64; break;
    case 4: base = Ws1; break;                             // rows 0..63 (ht part)
    case 5: base = Ws2; break;
    case 6: base = We; break;
    case 7: base = Wa; break;
    case 8: base = Wih; stride = 192; break;
    case 9: base = Whh; stride = 192; break;
  }
  const int qq = lane >> 4, col = nt * 16 + (lane & 15);
  union { unsigned short u[8]; uint4 v; } tmp;
#pragma unroll
  for (int jj = 0; jj < 8; jj++) {
    int k = ks * 32 + ((jj < 4) ? (qq * 4 + jj) : (16 + qq * 4 + (jj - 4)));
    tmp.u[jj] = bf16r(base[(size_t)k * stride + col]);
  }
  wfrag[(size_t)bid * 64 + lane] = tmp.v;
}

// ---------------- main fused kernel ----------------
// ROUND 16: r15 (2-stream, frag prefetch one phase ahead) + prefetch of the two
// remaining naked latency chains identified in the r15 post-mortem:
//  (a) epilogue fp32 ht reads (32/wave, L3/HBM ~500-900cy, were issued AT the tail)
//      -> issued before the res phase (~2 phases = 1-2K cy of cover); live range
//         kept short to stay under the 256-VGPR (256,2) budget;
//  (b) phase-head C-init loads: bn2 hoisted to staging; be/ba/GRU-gate biases and
//      Wp/bp to the pre-res prefetch batch. No numeric changes.
__global__ __launch_bounds__(256, 2) void gkt_main_kernel(
    const int* __restrict__ qt, const float* __restrict__ onehot, const float* __restrict__ ht,
    const float* __restrict__ nw, const float* __restrict__ bn2, const float* __restrict__ be,
    const float* __restrict__ ba, const float* __restrict__ bih, const float* __restrict__ bhh,
    const float* __restrict__ Wp, const float* __restrict__ bp, const float* __restrict__ eaw,
    const float* __restrict__ bs2, const float* __restrict__ adjw, const float* __restrict__ biasTab,
    const bf16x8* __restrict__ wfrag, float* __restrict__ out) {
  __shared__ __align__(128) unsigned short hbuf[4][2][64][16];  // [wave][stream][feat][tok]
  __shared__ __align__(16) float tokp[4][2][64];                // [wave][stream][param*16]
  __shared__ __align__(16) uint4 gfrag[40 * 64];                // Wih(0..23), Whh(24..39)

  const int tid = threadIdx.x;
  const int wv = tid >> 6, lane = tid & 63;
  const int q = lane >> 4, cl = lane & 15;
  const int t0 = (blockIdx.x * 4 + wv) * 32;
  const int b = t0 >> 10, c0 = t0 & 1023, c16 = c0 >> 4;

  const unsigned hbA = (unsigned)(size_t)&hbuf[wv][0][0][0] + lane * 8;  // tr-read addr A
  const unsigned hbB = hbA + 2048;                                      // stream B buffer
  const unsigned pbA = (unsigned)(size_t)&hbuf[wv][0][0][0] + cl * 32 + q * 8;  // pack base A
  const unsigned pbB = pbA + 2048;
  float* tpA = &tokp[wv][0][0];
  float* tpB = &tokp[wv][1][0];

  // ---- cooperative: 40 GRU frags -> LDS (10 per wave, once per block) ----
  {
    const uint4* wf4 = (const uint4*)wfrag;
#pragma unroll
    for (int i = 0; i < 10; i++) {
      int f = wv * 10 + i;
      gfrag[f * 64 + lane] = wf4[(64 + f) * 64 + lane];
    }
  }

  // ---- staging: per-token params + ht rows (transposed store, both streams) ----
  if (lane < 32) {
    const int s = lane >> 4, l = lane & 15;
    const int c = c0 + lane;
    float* tp = &tokp[wv][s][0];
    tp[l]      = onehot[(size_t)qt[b] * 1024 + c];  // mask
    tp[16 + l] = adjw[c];                           // adj[0][c]
    tp[32 + l] = adjw[1024 + c];                    // adj[1][c]
    tp[48 + l] = eaw[c];                            // g
  }
  {
    const float4* ht4 = (const float4*)ht;
#pragma unroll
    for (int i = 0; i < 8; i++) {
      float4 v = ht4[(size_t)t0 * 16 + i * 64 + lane];
      int e = i * 64 + lane;
      int tok = e >> 4, s = tok >> 4, tk = tok & 15, fb = (e & 15) * 4;
      hbuf[wv][s][fb + 0][tk] = bf16r(v.x);
      hbuf[wv][s][fb + 1][tk] = bf16r(v.y);
      hbuf[wv][s][fb + 2][tk] = bf16r(v.z);
      hbuf[wv][s][fb + 3][tk] = bf16r(v.w);
    }
  }

  auto ldB = [&](int frag) -> bf16x8 { return wfrag[frag * 64 + lane]; };
  auto ldG = [&](int fr) -> bf16x8 {   // 0..39 LDS, 40..47 L2
    return (fr < 40) ? *(const bf16x8*)&gfrag[fr * 64 + lane]
                     : wfrag[(64 + fr) * 64 + lane];
  };
  auto ldTP4 = [&](const float* tp, int base) -> f32x4 {
    return *(const f32x4*)(tp + base + q * 4);
  };
  auto packRow = [&](unsigned pb, int nt, float v0, float v1, float v2, float v3) {
    unsigned long long d = (unsigned long long)pkbf(v0, v1) |
                           ((unsigned long long)pkbf(v2, v3) << 32);
    dsw64(pb + nt * 512, d);
  };
  const f32x4* bt4 = (const f32x4*)biasTab;

  // ---- hoisted bn2 C-inits (phase-head chain heads in the k2 loop) ----
  float bn2v[8];
#pragma unroll
  for (int i = 0; i < 8; i++) bn2v[i] = bn2[(i >> 2) * 64 + (i & 3) * 16 + cl];

  // ---- prefetch F1 = Wn1h0 (consumed in P1 by both streams) ----
  bf16x8 fX[8], fY[8];
#pragma unroll
  for (int i = 0; i < 8; i++) fX[i] = ldB(FB_Wn1h0 + i);

  __syncthreads();   // staging visible

  const float wmix = fminf(fmaxf(nw[0], 0.1f), 0.9f);

  // ---- raw ht A-frags (live through GRU) ----
  bf16x8 xrA[2], xrB[2];
  ldA2_tr(hbA, xrA[0], xrA[1]);
  ldA2_tr(hbB, xrB[0], xrB[1]);
  bf16x8 xcA[2], xcB[2];
#pragma unroll
  for (int ks = 0; ks < 2; ks++) { xcA[ks] = clip5(xrA[ks]); xcB[ks] = clip5(xrB[ks]); }

  f32x4 nfA[4], nfB[4];

#pragma unroll
  for (int k2 = 0; k2 < 2; k2++) {
    // ===== P-odd: neighbor layer 1 (frags in fX); prefetch layer-2 frags into fY =====
#pragma unroll
    for (int i = 0; i < 8; i++) fY[i] = ldB((k2 ? FB_Wn2_1 : FB_Wn2_0) + i);
    f32x4 acA[4], acB[4];
#pragma unroll
    for (int nt = 0; nt < 4; nt++) {
      acA[nt] = bt4[((c16 * 3 + k2) * 4 + nt) * 64 + lane];
      acB[nt] = bt4[(((c16 + 1) * 3 + k2) * 4 + nt) * 64 + lane];
    }
#pragma unroll
    for (int ks = 0; ks < 2; ks++)
#pragma unroll
      for (int nt = 0; nt < 4; nt++) {
        acA[nt] = mfma16(xcA[ks], fX[ks * 4 + nt], acA[nt]);
        acB[nt] = mfma16(xcB[ks], fX[ks * 4 + nt], acB[nt]);
      }
#pragma unroll
    for (int nt = 0; nt < 4; nt++)
      packRow(pbA, nt, fmaxf(acA[nt][0], 0.f), fmaxf(acA[nt][1], 0.f),
                       fmaxf(acA[nt][2], 0.f), fmaxf(acA[nt][3], 0.f));
#pragma unroll
    for (int nt = 0; nt < 4; nt++)
      packRow(pbB, nt, fmaxf(acB[nt][0], 0.f), fmaxf(acB[nt][1], 0.f),
                       fmaxf(acB[nt][2], 0.f), fmaxf(acB[nt][3], 0.f));

    // ===== P-even: neighbor layer 2 (frags in fY); prefetch next phase into fX =====
#pragma unroll
    for (int i = 0; i < 8; i++) fX[i] = ldB((k2 ? FB_Ws1h : FB_Wn1h1) + i);
    bf16x8 a0, a1;
    f32x4 c2A[4], c2B[4];
#pragma unroll
    for (int nt = 0; nt < 4; nt++) {
      float bz = bn2v[k2 * 4 + nt];
      c2A[nt] = {bz, bz, bz, bz};
      c2B[nt] = c2A[nt];
    }
    ldA2_tr(hbA, a0, a1);
#pragma unroll
    for (int nt = 0; nt < 4; nt++) {
      c2A[nt] = mfma16(a0, fY[nt], c2A[nt]);
      c2A[nt] = mfma16(a1, fY[4 + nt], c2A[nt]);
    }
    ldA2_tr(hbB, a0, a1);
#pragma unroll
    for (int nt = 0; nt < 4; nt++) {
      c2B[nt] = mfma16(a0, fY[nt], c2B[nt]);
      c2B[nt] = mfma16(a1, fY[4 + nt], c2B[nt]);
    }
    {
      f32x4 avA = ldTP4(tpA, (1 + k2) * 16), avB = ldTP4(tpB, (1 + k2) * 16);
#pragma unroll
      for (int nt = 0; nt < 4; nt++)
#pragma unroll
        for (int r = 0; r < 4; r++) {
          float nbA = fminf(fmaxf(c2A[nt][r], 0.f), 5.f);
          float nbB = fminf(fmaxf(c2B[nt][r], 0.f), 5.f);
          float vA = avA[r] * nbA, vB = avB[r] * nbB;
          if (k2 == 0) {
            nfA[nt][r] = wmix * fminf(fmaxf(vA, -5.f), 5.f);
            nfB[nt][r] = wmix * fminf(fmaxf(vB, -5.f), 5.f);
          } else {
            nfA[nt][r] = fminf(fmaxf(nfA[nt][r] + (1.f - wmix) * vA, -5.f), 5.f);
            nfB[nt][r] = fminf(fmaxf(nfB[nt][r] + (1.f - wmix) * vB, -5.f), 5.f);
          }
        }
    }
  }

  // ---- self path (fX holds Ws1h from the last prefetch) ----
  bool anySelf = __any((lane < 32) && (tokp[wv][lane >> 4][lane & 15] > 0.5f));
  if (anySelf) {
#pragma unroll
    for (int i = 0; i < 8; i++) fY[i] = ldB(FB_Ws2 + i);   // prefetch self L2
    f32x4 acA[4], acB[4];
#pragma unroll
    for (int nt = 0; nt < 4; nt++) {
      acA[nt] = bt4[((c16 * 3 + 2) * 4 + nt) * 64 + lane];
      acB[nt] = bt4[(((c16 + 1) * 3 + 2) * 4 + nt) * 64 + lane];
    }
#pragma unroll
    for (int ks = 0; ks < 2; ks++)
#pragma unroll
      for (int nt = 0; nt < 4; nt++) {
        acA[nt] = mfma16(xrA[ks], fX[ks * 4 + nt], acA[nt]);   // raw ht
        acB[nt] = mfma16(xrB[ks], fX[ks * 4 + nt], acB[nt]);
      }
#pragma unroll
    for (int nt = 0; nt < 4; nt++)
      packRow(pbA, nt, fmaxf(acA[nt][0], 0.f), fmaxf(acA[nt][1], 0.f),
                       fmaxf(acA[nt][2], 0.f), fmaxf(acA[nt][3], 0.f));
#pragma unroll
    for (int nt = 0; nt < 4; nt++)
      packRow(pbB, nt, fmaxf(acB[nt][0], 0.f), fmaxf(acB[nt][1], 0.f),
                       fmaxf(acB[nt][2], 0.f), fmaxf(acB[nt][3], 0.f));
    bf16x8 a0, a1;
    f32x4 c2A[4], c2B[4];
#pragma unroll
    for (int nt = 0; nt < 4; nt++) {
      float bz = bs2[nt * 16 + cl];
      c2A[nt] = {bz, bz, bz, bz};
      c2B[nt] = c2A[nt];
    }
    ldA2_tr(hbA, a0, a1);
#pragma unroll
    for (int nt = 0; nt < 4; nt++) {
      c2A[nt] = mfma16(a0, fY[nt], c2A[nt]);
      c2A[nt] = mfma16(a1, fY[4 + nt], c2A[nt]);
    }
    ldA2_tr(hbB, a0, a1);
#pragma unroll
    for (int nt = 0; nt < 4; nt++) {
      c2B[nt] = mfma16(a0, fY[nt], c2B[nt]);
      c2B[nt] = mfma16(a1, fY[4 + nt], c2B[nt]);
    }
    {
      f32x4 mkA = ldTP4(tpA, 0), mkB = ldTP4(tpB, 0);
#pragma unroll
      for (int nt = 0; nt < 4; nt++)
#pragma unroll
        for (int r = 0; r < 4; r++) {
          float sfA = fminf(fmaxf(c2A[nt][r], 0.f), 10.f);
          float sfB = fminf(fmaxf(c2B[nt][r], 0.f), 10.f);
          nfA[nt][r] = (mkA[r] > 0.5f) ? sfA : nfA[nt][r];
          nfB[nt][r] = (mkB[r] > 0.5f) ? sfB : nfB[nt][r];
        }
    }
  }

  // ---- PREFETCH epilogue inputs (r16): fp32 ht + GRU/res bias columns + Wp/bp.
  // All pure-input loads, ~2 phases ahead of use; covered by res-phase compute.
  float htvA[16], htvB[16];
#pragma unroll
  for (int nt = 0; nt < 4; nt++)
#pragma unroll
    for (int r = 0; r < 4; r++) {
      htvA[nt * 4 + r] = ht[(size_t)(t0 + q * 4 + r) * 64 + nt * 16 + cl];
      htvB[nt * 4 + r] = ht[(size_t)(t0 + 16 + q * 4 + r) * 64 + nt * 16 + cl];
    }
  float bev[4], bav[4], brz[4], bzz[4], bnn[4], bhn[4], wp4[4];
#pragma unroll
  for (int nt = 0; nt < 4; nt++) {
    int col = nt * 16 + cl;
    bev[nt] = be[col];
    bav[nt] = ba[col];
    brz[nt] = bih[col] + bhh[col];
    bzz[nt] = bih[64 + col] + bhh[64 + col];
    bnn[nt] = bih[128 + col];
    bhn[nt] = bhh[128 + col];
    wp4[nt] = Wp[col];
  }
  const float bpv = bp[0];

  // ---- res = m - g*sigmoid(m@We+be)*m + g*tanh(m@Wa+ba) ----
#pragma unroll
  for (int i = 0; i < 8; i++) fX[i] = ldB(FB_We + i);   // We frags
#pragma unroll
  for (int nt = 0; nt < 4; nt++) packRow(pbA, nt, nfA[nt][0], nfA[nt][1], nfA[nt][2], nfA[nt][3]);
#pragma unroll
  for (int nt = 0; nt < 4; nt++) packRow(pbB, nt, nfB[nt][0], nfB[nt][1], nfB[nt][2], nfB[nt][3]);
  bf16x8 mfA[2], mfB[2];
  ldA2_tr(hbA, mfA[0], mfA[1]);
  ldA2_tr(hbB, mfB[0], mfB[1]);
  {
#pragma unroll
    for (int i = 0; i < 8; i++) fY[i] = ldB(FB_Wa + i);   // prefetch Wa under We compute
    f32x4 eA[4], eB[4];
#pragma unroll
    for (int nt = 0; nt < 4; nt++) {
      float bz = bev[nt];
      eA[nt] = {bz, bz, bz, bz};
      eB[nt] = eA[nt];
    }
#pragma unroll
    for (int ks = 0; ks < 2; ks++)
#pragma unroll
      for (int nt = 0; nt < 4; nt++) {
        eA[nt] = mfma16(mfA[ks], fX[ks * 4 + nt], eA[nt]);
        eB[nt] = mfma16(mfB[ks], fX[ks * 4 + nt], eB[nt]);
      }
    {
      f32x4 gvA = ldTP4(tpA, 48), gvB = ldTP4(tpB, 48);
#pragma unroll
      for (int nt = 0; nt < 4; nt++)
#pragma unroll
        for (int r = 0; r < 4; r++) {
          float mA = nfA[nt][r], mB = nfB[nt][r];
          nfA[nt][r] = mA - gvA[r] * sigmoidf_(eA[nt][r]) * mA;
          nfB[nt][r] = mB - gvB[r] * sigmoidf_(eB[nt][r]) * mB;
        }
    }
    f32x4 aA[4], aB[4];
#pragma unroll
    for (int nt = 0; nt < 4; nt++) {
      float bz = bav[nt];
      aA[nt] = {bz, bz, bz, bz};
      aB[nt] = aA[nt];
    }
#pragma unroll
    for (int ks = 0; ks < 2; ks++)
#pragma unroll
      for (int nt = 0; nt < 4; nt++) {
        aA[nt] = mfma16(mfA[ks], fY[ks * 4 + nt], aA[nt]);
        aB[nt] = mfma16(mfB[ks], fY[ks * 4 + nt], aB[nt]);
      }
    {
      f32x4 gvA = ldTP4(tpA, 48), gvB = ldTP4(tpB, 48);
#pragma unroll
      for (int nt = 0; nt < 4; nt++)
#pragma unroll
        for (int r = 0; r < 4; r++) {
          nfA[nt][r] += gvA[r] * tanhf_(aA[nt][r]);
          nfB[nt][r] += gvB[r] * tanhf_(aB[nt][r]);
        }
    }
  }

  // ---- GRU gates + output ----
#pragma unroll
  for (int nt = 0; nt < 4; nt++) packRow(pbA, nt, nfA[nt][0], nfA[nt][1], nfA[nt][2], nfA[nt][3]);
#pragma unroll
  for (int nt = 0; nt < 4; nt++) packRow(pbB, nt, nfB[nt][0], nfB[nt][1], nfB[nt][2], nfB[nt][3]);
  bf16x8 rfA[2], rfB[2];
  ldA2_tr(hbA, rfA[0], rfA[1]);
  ldA2_tr(hbB, rfB[0], rfB[1]);

  f32x4 gRA[4], gZA[4], gNA[4], gHA[4];
  f32x4 gRB[4], gZB[4], gNB[4], gHB[4];
#pragma unroll
  for (int nt = 0; nt < 4; nt++) {
    f32x4 v;
    v = {brz[nt], brz[nt], brz[nt], brz[nt]}; gRA[nt] = v; gRB[nt] = v;
    v = {bzz[nt], bzz[nt], bzz[nt], bzz[nt]}; gZA[nt] = v; gZB[nt] = v;
    v = {bnn[nt], bnn[nt], bnn[nt], bnn[nt]}; gNA[nt] = v; gNB[nt] = v;
    v = {bhn[nt], bhn[nt], bhn[nt], bhn[nt]}; gHA[nt] = v; gHB[nt] = v;
  }
#pragma unroll
  for (int ks = 0; ks < 2; ks++)
#pragma unroll
    for (int nt = 0; nt < 4; nt++) {
      bf16x8 bi_r = ldG(ks * 12 + nt);
      bf16x8 bh_r = ldG(24 + ks * 12 + nt);
      bf16x8 bi_z = ldG(ks * 12 + 4 + nt);
      bf16x8 bh_z = ldG(24 + ks * 12 + 4 + nt);
      bf16x8 bi_n = ldG(ks * 12 + 8 + nt);
      bf16x8 bh_n = ldG(24 + ks * 12 + 8 + nt);
      gRA[nt] = mfma16(rfA[ks], bi_r, gRA[nt]);
      gRA[nt] = mfma16(xrA[ks], bh_r, gRA[nt]);
      gZA[nt] = mfma16(rfA[ks], bi_z, gZA[nt]);
      gZA[nt] = mfma16(xrA[ks], bh_z, gZA[nt]);
      gNA[nt] = mfma16(rfA[ks], bi_n, gNA[nt]);
      gHA[nt] = mfma16(xrA[ks], bh_n, gHA[nt]);
      gRB[nt] = mfma16(rfB[ks], bi_r, gRB[nt]);
      gRB[nt] = mfma16(xrB[ks], bh_r, gRB[nt]);
      gZB[nt] = mfma16(rfB[ks], bi_z, gZB[nt]);
      gZB[nt] = mfma16(xrB[ks], bh_z, gZB[nt]);
      gNB[nt] = mfma16(rfB[ks], bi_n, gNB[nt]);
      gHB[nt] = mfma16(xrB[ks], bh_n, gHB[nt]);
    }

#pragma unroll
  for (int r = 0; r < 4; r++) {
    int tok = q * 4 + r;
    float part = 0.f;
#pragma unroll
    for (int nt = 0; nt < 4; nt++) {
      float rr = sigmoidf_(gRA[nt][r]);
      float zz = sigmoidf_(gZA[nt][r]);
      float nval = tanhf_(gNA[nt][r] + rr * gHA[nt][r]);
      float hnx = (1.f - zz) * nval + zz * htvA[nt * 4 + r];
      part += hnx * wp4[nt];
    }
    part += __shfl_xor(part, 1, 64);
    part += __shfl_xor(part, 2, 64);
    part += __shfl_xor(part, 4, 64);
    part += __shfl_xor(part, 8, 64);
    if (cl == 0) out[t0 + tok] = sigmoidf_(part + bpv);
  }
#pragma unroll
  for (int r = 0; r < 4; r++) {
    int tok = 16 + q * 4 + r;
    float part = 0.f;
#pragma unroll
    for (int nt = 0; nt < 4; nt++) {
      float rr = sigmoidf_(gRB[nt][r]);
      float zz = sigmoidf_(gZB[nt][r]);
      float nval = tanhf_(gNB[nt][r] + rr * gHB[nt][r]);
      float hnx = (1.f - zz) * nval + zz * htvB[nt * 4 + r];
      part += hnx * wp4[nt];
    }
    part += __shfl_xor(part, 1, 64);
    part += __shfl_xor(part, 2, 64);
    part += __shfl_xor(part, 4, 64);
    part += __shfl_xor(part, 8, 64);
    if (cl == 0) out[t0 + tok] = sigmoidf_(part + bpv);
  }
}

// ---------------- launcher ----------------
extern "C" void kernel_launch(void* const* d_in, const int* in_sizes, int n_in,
                              void* d_out, int out_size, void* d_ws, size_t ws_size,
                              hipStream_t stream) {
  const int*   qt     = (const int*)d_in[1];
  const float* ht     = (const float*)d_in[2];
  const float* onehot = (const float*)d_in[3];
  const float* kc     = (const float*)d_in[4];
  const float* graphs = (const float*)d_in[5];
  const float* nw     = (const float*)d_in[6];
  const float* Ws1    = (const float*)d_in[7];
  const float* bs1    = (const float*)d_in[8];
  const float* Ws2    = (const float*)d_in[9];
  const float* bs2    = (const float*)d_in[10];
  const float* Wn1    = (const float*)d_in[11];
  const float* bn1    = (const float*)d_in[12];
  const float* Wn2    = (const float*)d_in[13];
  const float* bn2    = (const float*)d_in[14];
  const float* eaw    = (const float*)d_in[15];
  const float* We     = (const float*)d_in[16];
  const float* be     = (const float*)d_in[17];
  const float* Wa     = (const float*)d_in[18];
  const float* ba     = (const float*)d_in[19];
  const float* Wih    = (const float*)d_in[20];
  const float* bih    = (const float*)d_in[21];
  const float* Whh    = (const float*)d_in[22];
  const float* bhh    = (const float*)d_in[23];
  const float* Wp     = (const float*)d_in[24];
  const float* bp     = (const float*)d_in[25];
  float* out = (float*)d_out;

  float* adjw    = (float*)((char*)d_ws + kAdjOff);
  float* biasTab = (float*)((char*)d_ws + kBiasOff);
  uint4* wfragU  = (uint4*)((char*)d_ws + kFragOff);

  prep_adj_kernel<<<8, 256, 0, stream>>>(qt, onehot, graphs, adjw);
  prep_bias_kernel<<<768, 256, 0, stream>>>(kc, Wn1, bn1, Ws1, bs1, biasTab);
  prep_wfrag_kernel<<<112, 64, 0, stream>>>(Wn1, Wn2, Ws1, Ws2, We, Wa, Wih, Whh, wfragU);
  gkt_main_kernel<<<2048, 256, 0, stream>>>(qt, onehot, ht, nw, bn2, be, ba, bih, bhh,
                                            Wp, bp, eaw, bs2, adjw, biasTab,
                                            (const bf16x8*)wfragU, out);
}

// Round 9
// 266.512 us; speedup vs baseline: 1.0692x; 1.0692x over previous
//
#include <hip/hip_runtime.h>

#define DEVINL __device__ __forceinline__

typedef __bf16 bf16x8 __attribute__((ext_vector_type(8)));
typedef float  f32x4  __attribute__((ext_vector_type(4)));
typedef unsigned u32x2 __attribute__((ext_vector_type(2)));

// ---------------- constants / ws layout ----------------
// B=256, C=1024, H=64, E=64, K=2, MI=128, tokens T = 262144
static constexpr size_t kAdjOff  = 0;                 // 2*1024 f32 (8 KB)
static constexpr size_t kBiasOff = 8192;              // 64*3*4*64*4 f32 = 786432 B
static constexpr size_t kFragOff = 8192 + 786432;     // 112 frags * 1024 B = 114688 B

// B-fragment bases (units: one frag = 64 lanes * 16 B)
static constexpr int FB_Wn1h0 = 0,  FB_Wn1h1 = 8,  FB_Wn2_0 = 16, FB_Wn2_1 = 24;
static constexpr int FB_Ws1h  = 32, FB_Ws2   = 40, FB_We    = 48, FB_Wa    = 56;
static constexpr int FB_Wih   = 64, FB_Whh   = 88;

// ---------------- helpers ----------------
DEVINL unsigned short bf16r(float f) {           // RTNE float->bf16
  unsigned u = __builtin_bit_cast(unsigned, f);
  unsigned r = ((u >> 16) & 1u) + 0x7FFFu;
  return (unsigned short)((u + r) >> 16);
}
DEVINL float sigmoidf_(float x) { return __builtin_amdgcn_rcpf(1.f + __expf(-x)); }
DEVINL float tanhf_(float x)    { return 1.f - 2.f * __builtin_amdgcn_rcpf(1.f + __expf(2.f * x)); }

// HW packed f32->bf16 (RNE, matches bf16r semantics on in-range values)
DEVINL unsigned pkbf(float a, float b) {
  unsigned d;
  asm("v_cvt_pk_bf16_f32 %0, %1, %2" : "=v"(d) : "v"(a), "v"(b));
  return d;
}

DEVINL f32x4 mfma16(bf16x8 a, bf16x8 b, f32x4 c) {
  return __builtin_amdgcn_mfma_f32_16x16x32_bf16(a, b, c, 0, 0, 0);
}

DEVINL unsigned clip2_(unsigned x) {   // clamp two packed bf16 to [-5,5]; exact repack
  float lo = __builtin_bit_cast(float, x << 16);
  float hi = __builtin_bit_cast(float, x & 0xFFFF0000u);
  lo = fminf(fmaxf(lo, -5.f), 5.f);
  hi = fminf(fmaxf(hi, -5.f), 5.f);
  return (__builtin_bit_cast(unsigned, lo) >> 16) | (__builtin_bit_cast(unsigned, hi) & 0xFFFF0000u);
}
DEVINL bf16x8 clip5(bf16x8 a) {
  uint4 u = __builtin_bit_cast(uint4, a);
  u.x = clip2_(u.x); u.y = clip2_(u.y); u.z = clip2_(u.z); u.w = clip2_(u.w);
  return __builtin_bit_cast(bf16x8, u);
}

// DS ops as volatile asm, no "memory" clobber (r14): mutual program order between
// volatile asm blocks + in-order DS queue give hbuf write->read->overwrite safety;
// ordinary global loads stay free to pipeline. tr-read keeps its internal
// lgkmcnt(0) (proven correct r13b); outputs early-clobber.
DEVINL void dsw64(unsigned addr, unsigned long long d) {
  asm volatile("ds_write_b64 %0, %1" :: "v"(addr), "v"(d));
}
DEVINL void ldA2_tr(unsigned addr, bf16x8& a0, bf16x8& a1) {
  u32x2 r0, r1, r2, r3;
  asm volatile(
      "ds_read_b64_tr_b16 %0, %4\n\t"
      "ds_read_b64_tr_b16 %1, %4 offset:512\n\t"
      "ds_read_b64_tr_b16 %2, %4 offset:1024\n\t"
      "ds_read_b64_tr_b16 %3, %4 offset:1536\n\t"
      "s_waitcnt lgkmcnt(0)"
      : "=&v"(r0), "=&v"(r1), "=&v"(r2), "=&v"(r3)
      : "v"(addr));
  uint4 u0{r0.x, r0.y, r1.x, r1.y};
  uint4 u1{r2.x, r2.y, r3.x, r3.y};
  a0 = __builtin_bit_cast(bf16x8, u0);
  a1 = __builtin_bit_cast(bf16x8, u1);
}

// ---------------- prep 1: adjacency vector (SPARSE: a0 has ~5 nonzeros) ----------------
__global__ void prep_adj_kernel(const int* __restrict__ qt, const float* __restrict__ onehot,
                                const float* __restrict__ graphs, float* __restrict__ adjw) {
  __shared__ float a0v[1024];
  __shared__ int   aidx[1024];
  __shared__ int   s_nnz;
  __shared__ float s_den;
  const int tid = threadIdx.x;
  const int k = blockIdx.x >> 2, chunk = blockIdx.x & 3;   // 8 blocks: 2k x 4 chunks of 256 d
  if (tid == 0) { s_nnz = 0; s_den = 0.f; }
  __syncthreads();
  const int q0 = qt[0];
  float lsum = 0.f;
#pragma unroll
  for (int i = 0; i < 4; i++) {
    int c = tid * 4 + i;
    float v = onehot[(size_t)q0 * 1024 + c];
    lsum += v;
    if (v != 0.f) { int p = atomicAdd(&s_nnz, 1); aidx[p] = c; a0v[p] = v; }
  }
#pragma unroll
  for (int off = 32; off >= 1; off >>= 1) lsum += __shfl_xor(lsum, off, 64);
  if ((tid & 63) == 0) atomicAdd(&s_den, lsum);
  __syncthreads();
  const float denom = fmaxf(s_den, 1.f);
  const int nnz = s_nnz;
  const int d = chunk * 256 + tid;
  const float* G = graphs + (size_t)k * 1048576 + d;
  float sum = 0.f;
  for (int j = 0; j < nnz; j++) sum += a0v[j] * G[(size_t)aidx[j] * 1024];
  adjw[k * 1024 + d] = fminf(fmaxf(sum / denom, -5.f), 5.f);
}

// ---------------- prep 2: per-c bias tables (kc folded into layer-1 bias) ----------------
// biasTab layout: [c16(64)][tab(3: n_k0,n_k1,self)][nt(4)][lane(64)][r(4)] fp32
__global__ void prep_bias_kernel(const float* __restrict__ kc, const float* __restrict__ Wn1,
                                 const float* __restrict__ bn1, const float* __restrict__ Ws1,
                                 const float* __restrict__ bs1, float* __restrict__ biasTab) {
  int gid = blockIdx.x * 256 + threadIdx.x;   // 196608 total
  int j = gid & 63;
  int c = (gid >> 6) & 1023;
  int tab = gid >> 16;                        // 0,1 neigh-k; 2 self
  const float* kcr = kc + (size_t)c * 64;
  float s;
  if (tab < 2) {
    s = bn1[tab * 64 + j];
    const float* W = Wn1 + ((size_t)tab * 256 + 192) * 64 + j;   // kc rows of neigh net
#pragma unroll 4
    for (int e = 0; e < 64; e++) s += fminf(fmaxf(kcr[e], -5.f), 5.f) * W[(size_t)e * 64];
  } else {
    s = bs1[j];
    const float* W = Ws1 + (size_t)64 * 64 + j;                  // kc rows of self net (unclipped)
#pragma unroll 4
    for (int e = 0; e < 64; e++) s += kcr[e] * W[(size_t)e * 64];
  }
  int c16 = c >> 4, rr = c & 3, qq = (c & 15) >> 2, nt = j >> 4;
  int lane = qq * 16 + (j & 15);
  biasTab[(size_t)((((c16 * 3 + tab) * 4 + nt) * 64 + lane)) * 4 + rr] = s;
}

// ---------------- prep 3: weights -> bf16 B-fragments (pre-swizzled, pi-permuted) --------
// B-frag (16x16x32): lane l slot j holds B[k = ks*32 + pi(q,j)][n = nt*16 + (l&15)],
// q = l>>4, pi(q,j) = (j<4) ? q*4+j : 16 + q*4 + (j-4).
// pi matches the k-order ds_read_b64_tr_b16 delivers from the transposed hbuf.
__global__ void prep_wfrag_kernel(const float* __restrict__ Wn1, const float* __restrict__ Wn2,
                                  const float* __restrict__ Ws1, const float* __restrict__ Ws2,
                                  const float* __restrict__ We,  const float* __restrict__ Wa,
                                  const float* __restrict__ Wih, const float* __restrict__ Whh,
                                  uint4* __restrict__ wfrag) {
  const int bid = blockIdx.x, lane = threadIdx.x;   // 112 blocks x 64 threads
  int mat, ks, nt;
  if (bid < 64) { mat = bid >> 3; ks = (bid >> 2) & 1; nt = bid & 3; }
  else { int f2 = bid - 64; mat = 8 + f2 / 24; int f = f2 % 24; ks = f / 12; nt = f % 12; }
  const float* base = Wn1; int stride = 64;
  switch (mat) {
    case 0: base = Wn1 + (size_t)128 * 64; break;          // Wn1 k0, ht rows 128..191
    case 1: base = Wn1 + (size_t)(256 + 128) * 64; break;  // Wn1 k1
    case 2: base = Wn2; break;
    case 3: base = Wn2 + (size_t)64 * 64; break;
    case 4: base = Ws1; break;                             // rows 0..63 (ht part)
    case 5: base = Ws2; break;
    case 6: base = We; break;
    case 7: base = Wa; break;
    case 8: base = Wih; stride = 192; break;
    case 9: base = Whh; stride = 192; break;
  }
  const int qq = lane >> 4, col = nt * 16 + (lane & 15);
  union { unsigned short u[8]; uint4 v; } tmp;
#pragma unroll
  for (int jj = 0; jj < 8; jj++) {
    int k = ks * 32 + ((jj < 4) ? (qq * 4 + jj) : (16 + qq * 4 + (jj - 4)));
    tmp.u[jj] = bf16r(base[(size_t)k * stride + col]);
  }
  wfrag[(size_t)bid * 64 + lane] = tmp.v;
}

// ---------------- main fused kernel ----------------
// ROUND 17: r15 structure (2-stream, one-phase-ahead frag prefetch; 85.4us proven)
// + GRU gate phase SPLIT BY STREAM. r16 post-mortem: arch-VGPR budget at (256,2) is
// 128 (accs live in AGPR side); r16's +69 arch prefetch regs spilled (WRITE 1->35MB).
// Splitting gates halves live accs (128->64 AGPR) and lets each stream's 16 fp32 ht
// epilogue loads issue just before that stream's 48-MFMA gate block (~400cy cover)
// with a short live range. Peak arch during gates ~90 < 128. gfrag LDS reads happen
// twice (cheap). Everything before the GRU section is byte-identical to r15.
__global__ __launch_bounds__(256, 2) void gkt_main_kernel(
    const int* __restrict__ qt, const float* __restrict__ onehot, const float* __restrict__ ht,
    const float* __restrict__ nw, const float* __restrict__ bn2, const float* __restrict__ be,
    const float* __restrict__ ba, const float* __restrict__ bih, const float* __restrict__ bhh,
    const float* __restrict__ Wp, const float* __restrict__ bp, const float* __restrict__ eaw,
    const float* __restrict__ bs2, const float* __restrict__ adjw, const float* __restrict__ biasTab,
    const bf16x8* __restrict__ wfrag, float* __restrict__ out) {
  __shared__ __align__(128) unsigned short hbuf[4][2][64][16];  // [wave][stream][feat][tok]
  __shared__ __align__(16) float tokp[4][2][64];                // [wave][stream][param*16]
  __shared__ __align__(16) uint4 gfrag[40 * 64];                // Wih(0..23), Whh(24..39)

  const int tid = threadIdx.x;
  const int wv = tid >> 6, lane = tid & 63;
  const int q = lane >> 4, cl = lane & 15;
  const int t0 = (blockIdx.x * 4 + wv) * 32;
  const int b = t0 >> 10, c0 = t0 & 1023, c16 = c0 >> 4;

  const unsigned hbA = (unsigned)(size_t)&hbuf[wv][0][0][0] + lane * 8;  // tr-read addr A
  const unsigned hbB = hbA + 2048;                                      // stream B buffer
  const unsigned pbA = (unsigned)(size_t)&hbuf[wv][0][0][0] + cl * 32 + q * 8;  // pack base A
  const unsigned pbB = pbA + 2048;
  float* tpA = &tokp[wv][0][0];
  float* tpB = &tokp[wv][1][0];

  // ---- cooperative: 40 GRU frags -> LDS (10 per wave, once per block) ----
  {
    const uint4* wf4 = (const uint4*)wfrag;
#pragma unroll
    for (int i = 0; i < 10; i++) {
      int f = wv * 10 + i;
      gfrag[f * 64 + lane] = wf4[(64 + f) * 64 + lane];
    }
  }

  // ---- staging: per-token params + ht rows (transposed store, both streams) ----
  if (lane < 32) {
    const int s = lane >> 4, l = lane & 15;
    const int c = c0 + lane;
    float* tp = &tokp[wv][s][0];
    tp[l]      = onehot[(size_t)qt[b] * 1024 + c];  // mask
    tp[16 + l] = adjw[c];                           // adj[0][c]
    tp[32 + l] = adjw[1024 + c];                    // adj[1][c]
    tp[48 + l] = eaw[c];                            // g
  }
  {
    const float4* ht4 = (const float4*)ht;
#pragma unroll
    for (int i = 0; i < 8; i++) {
      float4 v = ht4[(size_t)t0 * 16 + i * 64 + lane];
      int e = i * 64 + lane;
      int tok = e >> 4, s = tok >> 4, tk = tok & 15, fb = (e & 15) * 4;
      hbuf[wv][s][fb + 0][tk] = bf16r(v.x);
      hbuf[wv][s][fb + 1][tk] = bf16r(v.y);
      hbuf[wv][s][fb + 2][tk] = bf16r(v.z);
      hbuf[wv][s][fb + 3][tk] = bf16r(v.w);
    }
  }

  auto ldB = [&](int frag) -> bf16x8 { return wfrag[frag * 64 + lane]; };
  auto ldG = [&](int fr) -> bf16x8 {   // 0..39 LDS, 40..47 L2
    return (fr < 40) ? *(const bf16x8*)&gfrag[fr * 64 + lane]
                     : wfrag[(64 + fr) * 64 + lane];
  };
  auto ldTP4 = [&](const float* tp, int base) -> f32x4 {
    return *(const f32x4*)(tp + base + q * 4);
  };
  auto packRow = [&](unsigned pb, int nt, float v0, float v1, float v2, float v3) {
    unsigned long long d = (unsigned long long)pkbf(v0, v1) |
                           ((unsigned long long)pkbf(v2, v3) << 32);
    dsw64(pb + nt * 512, d);
  };
  const f32x4* bt4 = (const f32x4*)biasTab;

  // ---- prefetch F1 = Wn1h0 (consumed in P1 by both streams) ----
  bf16x8 fX[8], fY[8];
#pragma unroll
  for (int i = 0; i < 8; i++) fX[i] = ldB(FB_Wn1h0 + i);

  __syncthreads();   // staging visible

  const float wmix = fminf(fmaxf(nw[0], 0.1f), 0.9f);

  // ---- raw ht A-frags (live through GRU) ----
  bf16x8 xrA[2], xrB[2];
  ldA2_tr(hbA, xrA[0], xrA[1]);
  ldA2_tr(hbB, xrB[0], xrB[1]);
  bf16x8 xcA[2], xcB[2];
#pragma unroll
  for (int ks = 0; ks < 2; ks++) { xcA[ks] = clip5(xrA[ks]); xcB[ks] = clip5(xrB[ks]); }

  f32x4 nfA[4], nfB[4];

#pragma unroll
  for (int k2 = 0; k2 < 2; k2++) {
    // ===== P-odd: neighbor layer 1 (frags in fX); prefetch layer-2 frags into fY =====
#pragma unroll
    for (int i = 0; i < 8; i++) fY[i] = ldB((k2 ? FB_Wn2_1 : FB_Wn2_0) + i);
    f32x4 acA[4], acB[4];
#pragma unroll
    for (int nt = 0; nt < 4; nt++) {
      acA[nt] = bt4[((c16 * 3 + k2) * 4 + nt) * 64 + lane];
      acB[nt] = bt4[(((c16 + 1) * 3 + k2) * 4 + nt) * 64 + lane];
    }
#pragma unroll
    for (int ks = 0; ks < 2; ks++)
#pragma unroll
      for (int nt = 0; nt < 4; nt++) {
        acA[nt] = mfma16(xcA[ks], fX[ks * 4 + nt], acA[nt]);
        acB[nt] = mfma16(xcB[ks], fX[ks * 4 + nt], acB[nt]);
      }
#pragma unroll
    for (int nt = 0; nt < 4; nt++)
      packRow(pbA, nt, fmaxf(acA[nt][0], 0.f), fmaxf(acA[nt][1], 0.f),
                       fmaxf(acA[nt][2], 0.f), fmaxf(acA[nt][3], 0.f));
#pragma unroll
    for (int nt = 0; nt < 4; nt++)
      packRow(pbB, nt, fmaxf(acB[nt][0], 0.f), fmaxf(acB[nt][1], 0.f),
                       fmaxf(acB[nt][2], 0.f), fmaxf(acB[nt][3], 0.f));

    // ===== P-even: neighbor layer 2 (frags in fY); prefetch next phase into fX =====
#pragma unroll
    for (int i = 0; i < 8; i++) fX[i] = ldB((k2 ? FB_Ws1h : FB_Wn1h1) + i);
    bf16x8 a0, a1;
    f32x4 c2A[4], c2B[4];
#pragma unroll
    for (int nt = 0; nt < 4; nt++) {
      float bz = bn2[k2 * 64 + nt * 16 + cl];
      c2A[nt] = {bz, bz, bz, bz};
      c2B[nt] = c2A[nt];
    }
    ldA2_tr(hbA, a0, a1);
#pragma unroll
    for (int nt = 0; nt < 4; nt++) {
      c2A[nt] = mfma16(a0, fY[nt], c2A[nt]);
      c2A[nt] = mfma16(a1, fY[4 + nt], c2A[nt]);
    }
    ldA2_tr(hbB, a0, a1);
#pragma unroll
    for (int nt = 0; nt < 4; nt++) {
      c2B[nt] = mfma16(a0, fY[nt], c2B[nt]);
      c2B[nt] = mfma16(a1, fY[4 + nt], c2B[nt]);
    }
    {
      f32x4 avA = ldTP4(tpA, (1 + k2) * 16), avB = ldTP4(tpB, (1 + k2) * 16);
#pragma unroll
      for (int nt = 0; nt < 4; nt++)
#pragma unroll
        for (int r = 0; r < 4; r++) {
          float nbA = fminf(fmaxf(c2A[nt][r], 0.f), 5.f);
          float nbB = fminf(fmaxf(c2B[nt][r], 0.f), 5.f);
          float vA = avA[r] * nbA, vB = avB[r] * nbB;
          if (k2 == 0) {
            nfA[nt][r] = wmix * fminf(fmaxf(vA, -5.f), 5.f);
            nfB[nt][r] = wmix * fminf(fmaxf(vB, -5.f), 5.f);
          } else {
            nfA[nt][r] = fminf(fmaxf(nfA[nt][r] + (1.f - wmix) * vA, -5.f), 5.f);
            nfB[nt][r] = fminf(fmaxf(nfB[nt][r] + (1.f - wmix) * vB, -5.f), 5.f);
          }
        }
    }
  }

  // ---- self path (fX holds Ws1h from the last prefetch) ----
  bool anySelf = __any((lane < 32) && (tokp[wv][lane >> 4][lane & 15] > 0.5f));
  if (anySelf) {
#pragma unroll
    for (int i = 0; i < 8; i++) fY[i] = ldB(FB_Ws2 + i);   // prefetch self L2
    f32x4 acA[4], acB[4];
#pragma unroll
    for (int nt = 0; nt < 4; nt++) {
      acA[nt] = bt4[((c16 * 3 + 2) * 4 + nt) * 64 + lane];
      acB[nt] = bt4[(((c16 + 1) * 3 + 2) * 4 + nt) * 64 + lane];
    }
#pragma unroll
    for (int ks = 0; ks < 2; ks++)
#pragma unroll
      for (int nt = 0; nt < 4; nt++) {
        acA[nt] = mfma16(xrA[ks], fX[ks * 4 + nt], acA[nt]);   // raw ht
        acB[nt] = mfma16(xrB[ks], fX[ks * 4 + nt], acB[nt]);
      }
#pragma unroll
    for (int nt = 0; nt < 4; nt++)
      packRow(pbA, nt, fmaxf(acA[nt][0], 0.f), fmaxf(acA[nt][1], 0.f),
                       fmaxf(acA[nt][2], 0.f), fmaxf(acA[nt][3], 0.f));
#pragma unroll
    for (int nt = 0; nt < 4; nt++)
      packRow(pbB, nt, fmaxf(acB[nt][0], 0.f), fmaxf(acB[nt][1], 0.f),
                       fmaxf(acB[nt][2], 0.f), fmaxf(acB[nt][3], 0.f));
    bf16x8 a0, a1;
    f32x4 c2A[4], c2B[4];
#pragma unroll
    for (int nt = 0; nt < 4; nt++) {
      float bz = bs2[nt * 16 + cl];
      c2A[nt] = {bz, bz, bz, bz};
      c2B[nt] = c2A[nt];
    }
    ldA2_tr(hbA, a0, a1);
#pragma unroll
    for (int nt = 0; nt < 4; nt++) {
      c2A[nt] = mfma16(a0, fY[nt], c2A[nt]);
      c2A[nt] = mfma16(a1, fY[4 + nt], c2A[nt]);
    }
    ldA2_tr(hbB, a0, a1);
#pragma unroll
    for (int nt = 0; nt < 4; nt++) {
      c2B[nt] = mfma16(a0, fY[nt], c2B[nt]);
      c2B[nt] = mfma16(a1, fY[4 + nt], c2B[nt]);
    }
    {
      f32x4 mkA = ldTP4(tpA, 0), mkB = ldTP4(tpB, 0);
#pragma unroll
      for (int nt = 0; nt < 4; nt++)
#pragma unroll
        for (int r = 0; r < 4; r++) {
          float sfA = fminf(fmaxf(c2A[nt][r], 0.f), 10.f);
          float sfB = fminf(fmaxf(c2B[nt][r], 0.f), 10.f);
          nfA[nt][r] = (mkA[r] > 0.5f) ? sfA : nfA[nt][r];
          nfB[nt][r] = (mkB[r] > 0.5f) ? sfB : nfB[nt][r];
        }
    }
  }

  // ---- res = m - g*sigmoid(m@We+be)*m + g*tanh(m@Wa+ba) ----
#pragma unroll
  for (int i = 0; i < 8; i++) fX[i] = ldB(FB_We + i);   // We frags
#pragma unroll
  for (int nt = 0; nt < 4; nt++) packRow(pbA, nt, nfA[nt][0], nfA[nt][1], nfA[nt][2], nfA[nt][3]);
#pragma unroll
  for (int nt = 0; nt < 4; nt++) packRow(pbB, nt, nfB[nt][0], nfB[nt][1], nfB[nt][2], nfB[nt][3]);
  bf16x8 mfA[2], mfB[2];
  ldA2_tr(hbA, mfA[0], mfA[1]);
  ldA2_tr(hbB, mfB[0], mfB[1]);
  {
#pragma unroll
    for (int i = 0; i < 8; i++) fY[i] = ldB(FB_Wa + i);   // prefetch Wa under We compute
    f32x4 eA[4], eB[4];
#pragma unroll
    for (int nt = 0; nt < 4; nt++) {
      float bz = be[nt * 16 + cl];
      eA[nt] = {bz, bz, bz, bz};
      eB[nt] = eA[nt];
    }
#pragma unroll
    for (int ks = 0; ks < 2; ks++)
#pragma unroll
      for (int nt = 0; nt < 4; nt++) {
        eA[nt] = mfma16(mfA[ks], fX[ks * 4 + nt], eA[nt]);
        eB[nt] = mfma16(mfB[ks], fX[ks * 4 + nt], eB[nt]);
      }
    {
      f32x4 gvA = ldTP4(tpA, 48), gvB = ldTP4(tpB, 48);
#pragma unroll
      for (int nt = 0; nt < 4; nt++)
#pragma unroll
        for (int r = 0; r < 4; r++) {
          float mA = nfA[nt][r], mB = nfB[nt][r];
          nfA[nt][r] = mA - gvA[r] * sigmoidf_(eA[nt][r]) * mA;
          nfB[nt][r] = mB - gvB[r] * sigmoidf_(eB[nt][r]) * mB;
        }
    }
    f32x4 aA[4], aB[4];
#pragma unroll
    for (int nt = 0; nt < 4; nt++) {
      float bz = ba[nt * 16 + cl];
      aA[nt] = {bz, bz, bz, bz};
      aB[nt] = aA[nt];
    }
#pragma unroll
    for (int ks = 0; ks < 2; ks++)
#pragma unroll
      for (int nt = 0; nt < 4; nt++) {
        aA[nt] = mfma16(mfA[ks], fY[ks * 4 + nt], aA[nt]);
        aB[nt] = mfma16(mfB[ks], fY[ks * 4 + nt], aB[nt]);
      }
    {
      f32x4 gvA = ldTP4(tpA, 48), gvB = ldTP4(tpB, 48);
#pragma unroll
      for (int nt = 0; nt < 4; nt++)
#pragma unroll
        for (int r = 0; r < 4; r++) {
          nfA[nt][r] += gvA[r] * tanhf_(aA[nt][r]);
          nfB[nt][r] += gvB[r] * tanhf_(aB[nt][r]);
        }
    }
  }

  // ---- GRU gates + output (STREAM-SPLIT; per-stream ht prefetch under gate MFMAs) ----
#pragma unroll
  for (int nt = 0; nt < 4; nt++) packRow(pbA, nt, nfA[nt][0], nfA[nt][1], nfA[nt][2], nfA[nt][3]);
#pragma unroll
  for (int nt = 0; nt < 4; nt++) packRow(pbB, nt, nfB[nt][0], nfB[nt][1], nfB[nt][2], nfB[nt][3]);
  bf16x8 rfA[2], rfB[2];
  ldA2_tr(hbA, rfA[0], rfA[1]);
  ldA2_tr(hbB, rfB[0], rfB[1]);

  float brz[4], bzz[4], bnn[4], bhn[4], wp4[4];
#pragma unroll
  for (int nt = 0; nt < 4; nt++) {
    int col = nt * 16 + cl;
    brz[nt] = bih[col] + bhh[col];
    bzz[nt] = bih[64 + col] + bhh[64 + col];
    bnn[nt] = bih[128 + col];
    bhn[nt] = bhh[128 + col];
    wp4[nt] = Wp[col];
  }
  const float bpv = bp[0];

  auto gruStream = [&](const bf16x8* rf, const bf16x8* xr, int tbase) {
    // ht epilogue prefetch: issued before the 48-MFMA gate block (cover ~400cy);
    // live range = this stream only (16 arch regs).
    float htv[16];
#pragma unroll
    for (int nt = 0; nt < 4; nt++)
#pragma unroll
      for (int r = 0; r < 4; r++)
        htv[nt * 4 + r] = ht[(size_t)(t0 + tbase + q * 4 + r) * 64 + nt * 16 + cl];

    f32x4 gR[4], gZ[4], gN[4], gH[4];
#pragma unroll
    for (int nt = 0; nt < 4; nt++) {
      gR[nt] = {brz[nt], brz[nt], brz[nt], brz[nt]};
      gZ[nt] = {bzz[nt], bzz[nt], bzz[nt], bzz[nt]};
      gN[nt] = {bnn[nt], bnn[nt], bnn[nt], bnn[nt]};
      gH[nt] = {bhn[nt], bhn[nt], bhn[nt], bhn[nt]};
    }
#pragma unroll
    for (int ks = 0; ks < 2; ks++)
#pragma unroll
      for (int nt = 0; nt < 4; nt++) {
        bf16x8 bi_r = ldG(ks * 12 + nt);
        bf16x8 bh_r = ldG(24 + ks * 12 + nt);
        bf16x8 bi_z = ldG(ks * 12 + 4 + nt);
        bf16x8 bh_z = ldG(24 + ks * 12 + 4 + nt);
        bf16x8 bi_n = ldG(ks * 12 + 8 + nt);
        bf16x8 bh_n = ldG(24 + ks * 12 + 8 + nt);
        gR[nt] = mfma16(rf[ks], bi_r, gR[nt]);
        gR[nt] = mfma16(xr[ks], bh_r, gR[nt]);   // gi_r + gh_r chained
        gZ[nt] = mfma16(rf[ks], bi_z, gZ[nt]);
        gZ[nt] = mfma16(xr[ks], bh_z, gZ[nt]);
        gN[nt] = mfma16(rf[ks], bi_n, gN[nt]);   // in_
        gH[nt] = mfma16(xr[ks], bh_n, gH[nt]);   // hn
      }

#pragma unroll
    for (int r = 0; r < 4; r++) {
      int tok = tbase + q * 4 + r;
      float part = 0.f;
#pragma unroll
      for (int nt = 0; nt < 4; nt++) {
        float rr = sigmoidf_(gR[nt][r]);
        float zz = sigmoidf_(gZ[nt][r]);
        float nval = tanhf_(gN[nt][r] + rr * gH[nt][r]);
        float hnx = (1.f - zz) * nval + zz * htv[nt * 4 + r];
        part += hnx * wp4[nt];
      }
      part += __shfl_xor(part, 1, 64);
      part += __shfl_xor(part, 2, 64);
      part += __shfl_xor(part, 4, 64);
      part += __shfl_xor(part, 8, 64);
      if (cl == 0) out[t0 + tok] = sigmoidf_(part + bpv);
    }
  };
  gruStream(rfA, xrA, 0);
  gruStream(rfB, xrB, 16);
}

// ---------------- launcher ----------------
extern "C" void kernel_launch(void* const* d_in, const int* in_sizes, int n_in,
                              void* d_out, int out_size, void* d_ws, size_t ws_size,
                              hipStream_t stream) {
  const int*   qt     = (const int*)d_in[1];
  const float* ht     = (const float*)d_in[2];
  const float* onehot = (const float*)d_in[3];
  const float* kc     = (const float*)d_in[4];
  const float* graphs = (const float*)d_in[5];
  const float* nw     = (const float*)d_in[6];
  const float* Ws1    = (const float*)d_in[7];
  const float* bs1    = (const float*)d_in[8];
  const float* Ws2    = (const float*)d_in[9];
  const float* bs2    = (const float*)d_in[10];
  const float* Wn1    = (const float*)d_in[11];
  const float* bn1    = (const float*)d_in[12];
  const float* Wn2    = (const float*)d_in[13];
  const float* bn2    = (const float*)d_in[14];
  const float* eaw    = (const float*)d_in[15];
  const float* We     = (const float*)d_in[16];
  const float* be     = (const float*)d_in[17];
  const float* Wa     = (const float*)d_in[18];
  const float* ba     = (const float*)d_in[19];
  const float* Wih    = (const float*)d_in[20];
  const float* bih    = (const float*)d_in[21];
  const float* Whh    = (const float*)d_in[22];
  const float* bhh    = (const float*)d_in[23];
  const float* Wp     = (const float*)d_in[24];
  const float* bp     = (const float*)d_in[25];
  float* out = (float*)d_out;

  float* adjw    = (float*)((char*)d_ws + kAdjOff);
  float* biasTab = (float*)((char*)d_ws + kBiasOff);
  uint4* wfragU  = (uint4*)((char*)d_ws + kFragOff);

  prep_adj_kernel<<<8, 256, 0, stream>>>(qt, onehot, graphs, adjw);
  prep_bias_kernel<<<768, 256, 0, stream>>>(kc, Wn1, bn1, Ws1, bs1, biasTab);
  prep_wfrag_kernel<<<112, 64, 0, stream>>>(Wn1, Wn2, Ws1, Ws2, We, Wa, Wih, Whh, wfragU);
  gkt_main_kernel<<<2048, 256, 0, stream>>>(qt, onehot, ht, nw, bn2, be, ba, bih, bhh,
                                            Wp, bp, eaw, bs2, adjw, biasTab,
                                            (const bf16x8*)wfragU, out);
}